// Round 10
// baseline (383.697 us; speedup 1.0000x reference)
//
#include <hip/hip_runtime.h>
#include <math.h>

#define N_NODES 50000
#define N_EDGES 1600000
#define N_GRAPH 500
#define CHUNKS 128
#define EPC (N_EDGES / CHUNKS)  // 12500 edges per chunk
#define NP1 (N_NODES + 1)

// ---------- helpers ----------
__device__ __forceinline__ float rl(float v, int k) {
    return __int_as_float(__builtin_amdgcn_readlane(__float_as_int(v), k));
}

// ---------- histsort: per-chunk LDS histogram -> in-LDS exclusive scan ->
//            chunk-local dst-sorted scatter. No global atomics.
//            Emits locs[c][d] (u16 exclusive offsets, sentinel at d=N) and csrc_chunk.
__global__ __launch_bounds__(1024) void histsort_kernel(const int* __restrict__ src,
                                                        const int* __restrict__ dst,
                                                        int* __restrict__ csrc_chunk,
                                                        unsigned short* __restrict__ locs,
                                                        unsigned short* __restrict__ lr_g) {
    __shared__ unsigned packed[N_NODES / 2];  // 100 KB: 2x16-bit counters, then prefixes
    __shared__ unsigned aux[1024];
    const int c = blockIdx.x;
    const int s0 = c * EPC;
    const int tid = threadIdx.x;

    for (int i = tid; i < N_NODES / 2; i += 1024) packed[i] = 0;
    __syncthreads();

    // count + per-edge local rank
    for (int e = s0 + tid; e < s0 + EPC; e += 1024) {
        int d = dst[e];
        int sh = (d & 1) * 16;
        unsigned old = atomicAdd(&packed[d >> 1], 1u << sh);
        lr_g[e] = (unsigned short)((old >> sh) & 0xffffu);
    }
    __syncthreads();

    // in-place exclusive scan over 50000 16-bit counters (prefix <= 12500, fits 16b)
    const int W = 25;  // words per thread
    int w0 = tid * W;
    int w1 = min(w0 + W, N_NODES / 2);
    unsigned run = 0;
    for (int i = w0; i < w1; i++) {
        unsigned v = packed[i];
        unsigned lo = v & 0xffffu, hi = v >> 16;
        packed[i] = run | ((run + lo) << 16);
        run += lo + hi;
    }
    aux[tid] = run;
    __syncthreads();
    for (int off = 1; off < 1024; off <<= 1) {
        unsigned t = (tid >= off) ? aux[tid - off] : 0;
        __syncthreads();
        aux[tid] += t;
        __syncthreads();
    }
    unsigned b0 = (tid == 0) ? 0 : aux[tid - 1];
    if (b0) {
        unsigned addv = b0 | (b0 << 16);
        for (int i = w0; i < w1; i++) packed[i] += addv;
    }
    __syncthreads();

    // scatter this chunk's edges into chunk-local dst-sorted order
    int* outc = csrc_chunk + (size_t)c * EPC;
    for (int e = s0 + tid; e < s0 + EPC; e += 1024) {
        int d = dst[e];
        unsigned pw = packed[d >> 1];
        unsigned loc = (d & 1) ? (pw >> 16) : (pw & 0xffffu);
        outc[loc + lr_g[e]] = src[e];
    }
    // emit loc per node (+ sentinel)
    unsigned short* lc = locs + (size_t)c * NP1;
    for (int d = tid; d <= N_NODES; d += 1024) {
        unsigned short loc;
        if (d == N_NODES) {
            loc = (unsigned short)EPC;
        } else {
            unsigned pw = packed[d >> 1];
            loc = (unsigned short)((d & 1) ? (pw >> 16) : (pw & 0xffffu));
        }
        lc[d] = loc;
    }
}

// ---------- base + scan1 fused ----------
__global__ __launch_bounds__(1024) void base_scan1_kernel(const unsigned short* __restrict__ locs,
                                                          unsigned short* __restrict__ base,
                                                          int* __restrict__ deg,
                                                          int* __restrict__ part, int N) {
    int d = blockIdx.x * 1024 + threadIdx.x;
    int run = 0;
    if (d < N) {
#pragma unroll 8
        for (int c = 0; c < CHUNKS; c++) {
            int l0 = locs[(size_t)c * NP1 + d];
            int l1 = locs[(size_t)c * NP1 + d + 1];
            base[(size_t)c * N + d] = (unsigned short)run;
            run += l1 - l0;
        }
        deg[d] = run;
    }
    int v = run;
#pragma unroll
    for (int o = 32; o >= 1; o >>= 1) v += __shfl_xor(v, o);
    __shared__ int red[16];
    if ((threadIdx.x & 63) == 0) red[threadIdx.x >> 6] = v;
    __syncthreads();
    if (threadIdx.x == 0) {
        int s = 0;
#pragma unroll
        for (int k = 0; k < 16; k++) s += red[k];
        part[blockIdx.x] = s;
    }
}

__global__ void scan2_kernel(int* __restrict__ part, int nb) {
    int lane = threadIdx.x;
    int v = (lane < nb) ? part[lane] : 0;
    int orig = v;
#pragma unroll
    for (int o = 1; o < 64; o <<= 1) {
        int t = __shfl_up(v, o);
        if (lane >= o) v += t;
    }
    if (lane < nb) part[lane] = v - orig;
    if (lane == nb - 1) part[nb] = v;
}

__global__ __launch_bounds__(1024) void scan3_kernel(const int* __restrict__ deg,
                                                     const int* __restrict__ part,
                                                     int* __restrict__ rowptr, int N) {
    int i = blockIdx.x * 1024 + threadIdx.x;
    int lane = threadIdx.x & 63;
    int w = threadIdx.x >> 6;
    int v = (i < N) ? deg[i] : 0;
    int inc = v;
#pragma unroll
    for (int o = 1; o < 64; o <<= 1) {
        int t = __shfl_up(inc, o);
        if (lane >= o) inc += t;
    }
    __shared__ int wsum[16];
    if (lane == 63) wsum[w] = inc;
    __syncthreads();
    if (threadIdx.x < 16) {
        int x = wsum[threadIdx.x];
        int xo = x;
#pragma unroll
        for (int o = 1; o < 16; o <<= 1) {
            int t = __shfl_up(x, o);
            if ((int)threadIdx.x >= o) x += t;
        }
        wsum[threadIdx.x] = x - xo;
    }
    __syncthreads();
    int b = part[blockIdx.x] + wsum[w];
    if (i < N) {
        rowptr[i] = b + inc - v;
        if (i == N - 1) rowptr[N] = b + inc;
    }
}

// ---------- gatherfill: one wave per node, lane covers 2 chunks; node-contiguous writes ----------
__global__ __launch_bounds__(256) void gatherfill_kernel(const int* __restrict__ csrc_chunk,
                                                         const unsigned short* __restrict__ locs,
                                                         const unsigned short* __restrict__ base,
                                                         const int* __restrict__ rowptr,
                                                         int* __restrict__ csr_src) {
    const int perXcd = N_NODES / 8;  // 6250
    int xcd = blockIdx.x & 7;
    int idx = (blockIdx.x >> 3) * 4 + (threadIdx.x >> 6);
    if (idx >= perXcd) return;
    int wid = xcd * perXcd + idx;
    int lane = threadIdx.x & 63;
    int rp = rowptr[wid];
#pragma unroll
    for (int cc = 0; cc < 2; cc++) {
        int c = lane + cc * 64;
        const unsigned short* lc = locs + (size_t)c * NP1;
        int l0 = lc[wid];
        int l1 = lc[wid + 1];
        int cnt = l1 - l0;
        int ob = rp + (int)base[(size_t)c * N_NODES + wid];
        const int* in = csrc_chunk + (size_t)c * EPC + l0;
        for (int i = 0; i < cnt; i++) csr_src[ob + i] = in[i];
    }
}

// ---------- pair-node aggregation: one wave per 2 nodes (contiguous CSR range) ----------
__global__ __launch_bounds__(256) void agg_kernel(const float* __restrict__ y,
                                                  const int* __restrict__ rowptr,
                                                  const int* __restrict__ csr_src,
                                                  float* __restrict__ u, int N) {
    int pair = (blockIdx.x * 256 + threadIdx.x) >> 6;
    int n0 = pair * 2;
    if (n0 >= N) return;
    int lane = threadIdx.x & 63;
    int q = lane >> 4;   // edge slot 0..3
    int r = lane & 15;   // feature quad 0..15
    int s = rowptr[n0];
    int b = rowptr[n0 + 1];
    int e = rowptr[n0 + 2];
    float4 A = make_float4(0.f, 0.f, 0.f, 0.f);
    float4 B = make_float4(0.f, 0.f, 0.f, 0.f);
    int j = s;
    for (; j + 32 <= e; j += 32) {
        int i0 = j + q,      i1 = j + 4 + q,  i2 = j + 8 + q,  i3 = j + 12 + q;
        int i4 = j + 16 + q, i5 = j + 20 + q, i6 = j + 24 + q, i7 = j + 28 + q;
        int s0 = csr_src[i0], s1 = csr_src[i1], s2 = csr_src[i2], s3 = csr_src[i3];
        int s4 = csr_src[i4], s5 = csr_src[i5], s6 = csr_src[i6], s7 = csr_src[i7];
        float4 v0 = *(const float4*)(y + (size_t)s0 * 64 + r * 4);
        float4 v1 = *(const float4*)(y + (size_t)s1 * 64 + r * 4);
        float4 v2 = *(const float4*)(y + (size_t)s2 * 64 + r * 4);
        float4 v3 = *(const float4*)(y + (size_t)s3 * 64 + r * 4);
        float4 v4 = *(const float4*)(y + (size_t)s4 * 64 + r * 4);
        float4 v5 = *(const float4*)(y + (size_t)s5 * 64 + r * 4);
        float4 v6 = *(const float4*)(y + (size_t)s6 * 64 + r * 4);
        float4 v7 = *(const float4*)(y + (size_t)s7 * 64 + r * 4);
        if (i0 < b) { A.x += v0.x; A.y += v0.y; A.z += v0.z; A.w += v0.w; }
        else        { B.x += v0.x; B.y += v0.y; B.z += v0.z; B.w += v0.w; }
        if (i1 < b) { A.x += v1.x; A.y += v1.y; A.z += v1.z; A.w += v1.w; }
        else        { B.x += v1.x; B.y += v1.y; B.z += v1.z; B.w += v1.w; }
        if (i2 < b) { A.x += v2.x; A.y += v2.y; A.z += v2.z; A.w += v2.w; }
        else        { B.x += v2.x; B.y += v2.y; B.z += v2.z; B.w += v2.w; }
        if (i3 < b) { A.x += v3.x; A.y += v3.y; A.z += v3.z; A.w += v3.w; }
        else        { B.x += v3.x; B.y += v3.y; B.z += v3.z; B.w += v3.w; }
        if (i4 < b) { A.x += v4.x; A.y += v4.y; A.z += v4.z; A.w += v4.w; }
        else        { B.x += v4.x; B.y += v4.y; B.z += v4.z; B.w += v4.w; }
        if (i5 < b) { A.x += v5.x; A.y += v5.y; A.z += v5.z; A.w += v5.w; }
        else        { B.x += v5.x; B.y += v5.y; B.z += v5.z; B.w += v5.w; }
        if (i6 < b) { A.x += v6.x; A.y += v6.y; A.z += v6.z; A.w += v6.w; }
        else        { B.x += v6.x; B.y += v6.y; B.z += v6.z; B.w += v6.w; }
        if (i7 < b) { A.x += v7.x; A.y += v7.y; A.z += v7.z; A.w += v7.w; }
        else        { B.x += v7.x; B.y += v7.y; B.z += v7.z; B.w += v7.w; }
    }
#pragma unroll
    for (int m = 0; m < 8; m++) {
        int ii = j + 4 * m + q;
        if (ii < e) {
            int si = csr_src[ii];
            float4 v = *(const float4*)(y + (size_t)si * 64 + r * 4);
            if (ii < b) { A.x += v.x; A.y += v.y; A.z += v.z; A.w += v.w; }
            else        { B.x += v.x; B.y += v.y; B.z += v.z; B.w += v.w; }
        }
    }
    // reduce edge slots
    A.x += __shfl_xor(A.x, 16); A.y += __shfl_xor(A.y, 16);
    A.z += __shfl_xor(A.z, 16); A.w += __shfl_xor(A.w, 16);
    A.x += __shfl_xor(A.x, 32); A.y += __shfl_xor(A.y, 32);
    A.z += __shfl_xor(A.z, 32); A.w += __shfl_xor(A.w, 32);
    B.x += __shfl_xor(B.x, 16); B.y += __shfl_xor(B.y, 16);
    B.z += __shfl_xor(B.z, 16); B.w += __shfl_xor(B.w, 16);
    B.x += __shfl_xor(B.x, 32); B.y += __shfl_xor(B.y, 32);
    B.z += __shfl_xor(B.z, 32); B.w += __shfl_xor(B.w, 32);
    if (lane < 16) {
        float4 self = *(const float4*)(y + (size_t)n0 * 64 + r * 4);
        A.x += self.x; A.y += self.y; A.z += self.z; A.w += self.w;
        *(float4*)(u + (size_t)n0 * 64 + r * 4) = A;
    } else if (lane < 32) {
        float4 self = *(const float4*)(y + (size_t)(n0 + 1) * 64 + r * 4);
        B.x += self.x; B.y += self.y; B.z += self.z; B.w += self.w;
        *(float4*)(u + (size_t)(n0 + 1) * 64 + r * 4) = B;
    }
}

// ---------- gemm0: y0 = x @ W1_0 (N x 128 -> N x 64), register weights ----------
__global__ __launch_bounds__(256) void gemm0_kernel(const float* __restrict__ x,
                                                    const float* __restrict__ W1,
                                                    float* __restrict__ y0,
                                                    int N, int totalWaves) {
    int lane = threadIdx.x & 63;
    int wid = (blockIdx.x * 256 + threadIdx.x) >> 6;
    float w[64];
#pragma unroll
    for (int k = 0; k < 64; k++) w[k] = W1[k * 64 + lane];
    for (int node = wid; node < N; node += totalWaves) {
        float xa = x[node * 128 + lane];
        float a0 = 0.f, a1 = 0.f, a2 = 0.f, a3 = 0.f;
#pragma unroll
        for (int k = 0; k < 64; k += 4) {
            a0 = fmaf(rl(xa, k + 0), w[k + 0], a0);
            a1 = fmaf(rl(xa, k + 1), w[k + 1], a1);
            a2 = fmaf(rl(xa, k + 2), w[k + 2], a2);
            a3 = fmaf(rl(xa, k + 3), w[k + 3], a3);
        }
        y0[node * 64 + lane] = (a0 + a1) + (a2 + a3);
    }
#pragma unroll
    for (int k = 0; k < 64; k++) w[k] = W1[(64 + k) * 64 + lane];
    for (int node = wid; node < N; node += totalWaves) {
        float xb = x[node * 128 + 64 + lane];
        float a0 = 0.f, a1 = 0.f, a2 = 0.f, a3 = 0.f;
#pragma unroll
        for (int k = 0; k < 64; k += 4) {
            a0 = fmaf(rl(xb, k + 0), w[k + 0], a0);
            a1 = fmaf(rl(xb, k + 1), w[k + 1], a1);
            a2 = fmaf(rl(xb, k + 2), w[k + 2], a2);
            a3 = fmaf(rl(xb, k + 3), w[k + 3], a3);
        }
        y0[node * 64 + lane] += (a0 + a1) + (a2 + a3);
    }
}

// ---------- fused mlpAB (layers 0,1) ----------
template <int LAYER>
__global__ __launch_bounds__(256) void mlpAB_kernel(const float* __restrict__ u,
                                                    const float* __restrict__ b1,
                                                    const float* __restrict__ W2,
                                                    const float* __restrict__ b2,
                                                    const float* __restrict__ W1n,
                                                    const float* __restrict__ Wm,
                                                    float* __restrict__ ynext,
                                                    float* __restrict__ score,
                                                    int N, int totalWaves) {
    int lane = threadIdx.x & 63;
    int wid = (blockIdx.x * 256 + threadIdx.x) >> 6;
    float w2[64], w1[64];
#pragma unroll
    for (int k = 0; k < 64; k++) w2[k] = W2[k * 64 + lane];
#pragma unroll
    for (int k = 0; k < 64; k++) w1[k] = W1n[k * 64 + lane];
    float bb1 = b1[lane], bb2 = b2[lane], wm = Wm[LAYER * 64 + lane];

    int node = wid;
    float uin = (node < N) ? u[node * 64 + lane] : 0.f;
    for (; node < N; node += totalWaves) {
        int nn = node + totalWaves;
        float unext = (nn < N) ? u[nn * 64 + lane] : 0.f;
        float t = fmaxf(uin + bb1, 0.f);
        float a0 = 0.f, a1 = 0.f, a2 = 0.f, a3 = 0.f;
#pragma unroll
        for (int k = 0; k < 64; k += 4) {
            a0 = fmaf(rl(t, k + 0), w2[k + 0], a0);
            a1 = fmaf(rl(t, k + 1), w2[k + 1], a1);
            a2 = fmaf(rl(t, k + 2), w2[k + 2], a2);
            a3 = fmaf(rl(t, k + 3), w2[k + 3], a3);
        }
        float h = fmaxf(bb2 + ((a0 + a1) + (a2 + a3)), 0.f);
        float p = h * wm;
#pragma unroll
        for (int o = 32; o >= 1; o >>= 1) p += __shfl_xor(p, o);
        if (lane == 0) {
            if (LAYER == 0) score[node] = p;
            else score[node] += p;
        }
        float y0 = 0.f, y1 = 0.f, y2 = 0.f, y3 = 0.f;
#pragma unroll
        for (int k = 0; k < 64; k += 4) {
            y0 = fmaf(rl(h, k + 0), w1[k + 0], y0);
            y1 = fmaf(rl(h, k + 1), w1[k + 1], y1);
            y2 = fmaf(rl(h, k + 2), w1[k + 2], y2);
            y3 = fmaf(rl(h, k + 3), w1[k + 3], y3);
        }
        ynext[node * 64 + lane] = (y0 + y1) + (y2 + y3);
        uin = unext;
    }
}

// ---------- mlpA2 (layer 2) ----------
__global__ __launch_bounds__(256) void mlpA2_kernel(const float* __restrict__ u,
                                                    const float* __restrict__ b1,
                                                    const float* __restrict__ W2,
                                                    const float* __restrict__ b2,
                                                    const float* __restrict__ Wm,
                                                    float* __restrict__ score,
                                                    int N, int totalWaves) {
    int lane = threadIdx.x & 63;
    int wid = (blockIdx.x * 256 + threadIdx.x) >> 6;
    float w2[64];
#pragma unroll
    for (int k = 0; k < 64; k++) w2[k] = W2[k * 64 + lane];
    float bb1 = b1[lane], bb2 = b2[lane], wm = Wm[2 * 64 + lane];

    int node = wid;
    float uin = (node < N) ? u[node * 64 + lane] : 0.f;
    for (; node < N; node += totalWaves) {
        int nn = node + totalWaves;
        float unext = (nn < N) ? u[nn * 64 + lane] : 0.f;
        float t = fmaxf(uin + bb1, 0.f);
        float a0 = 0.f, a1 = 0.f, a2 = 0.f, a3 = 0.f;
#pragma unroll
        for (int k = 0; k < 64; k += 4) {
            a0 = fmaf(rl(t, k + 0), w2[k + 0], a0);
            a1 = fmaf(rl(t, k + 1), w2[k + 1], a1);
            a2 = fmaf(rl(t, k + 2), w2[k + 2], a2);
            a3 = fmaf(rl(t, k + 3), w2[k + 3], a3);
        }
        float h = bb2 + ((a0 + a1) + (a2 + a3));
        float p = h * wm;
#pragma unroll
        for (int o = 32; o >= 1; o >>= 1) p += __shfl_xor(p, o);
        if (lane == 0) score[node] += p;
        uin = unext;
    }
}

// ---------- edge softmax + new_score ----------
__global__ __launch_bounds__(256) void edge_softmax_kernel(const float* __restrict__ score,
                                                           const int* __restrict__ rowptr,
                                                           const int* __restrict__ csr_src,
                                                           const float* __restrict__ bm,
                                                           float* __restrict__ nsf, int N) {
    int wid = (blockIdx.x * blockDim.x + threadIdx.x) >> 6;
    int lane = threadIdx.x & 63;
    if (wid >= N) return;
    float b = bm[0];
    float sd = score[wid] + b;
    int start = rowptr[wid];
    int end = rowptr[wid + 1];
    bool has0 = (start + lane < end);
    float ss0 = 0.f;
    float m = -INFINITY;
    if (has0) {
        ss0 = score[csr_src[start + lane]] + b;
        m = ss0 * sd;
    }
    for (int j = start + 64 + lane; j < end; j += 64) {
        float ss = score[csr_src[j]] + b;
        m = fmaxf(m, ss * sd);
    }
#pragma unroll
    for (int o = 32; o >= 1; o >>= 1) m = fmaxf(m, __shfl_xor(m, o));
    float se = 0.f, swe = 0.f;
    if (m > -INFINITY) {
        if (has0) {
            float e0 = expf(ss0 * sd - m);
            se += e0;
            swe += ss0 * e0;
        }
        for (int j = start + 64 + lane; j < end; j += 64) {
            float ss = score[csr_src[j]] + b;
            float e = expf(ss * sd - m);
            se += e;
            swe += ss * e;
        }
#pragma unroll
        for (int o = 32; o >= 1; o >>= 1) {
            se += __shfl_xor(se, o);
            swe += __shfl_xor(swe, o);
        }
    }
    float ns = (se > 0.f) ? (swe / se) : 0.f;
    if (lane == 0) nsf[wid] = sd + ns;
}

// ---------- fused graph-segment softmax: one block per graph ----------
__global__ __launch_bounds__(256) void graph_softmax_kernel(const float* __restrict__ nsf,
                                                            const int* __restrict__ batch,
                                                            float* __restrict__ out, int N) {
    int g = blockIdx.x;
    int tid = threadIdx.x;
    int lo = 0, hi = N;
    while (lo < hi) { int mid = (lo + hi) >> 1; if (batch[mid] < g) lo = mid + 1; else hi = mid; }
    int s0 = lo;
    hi = N;
    while (lo < hi) { int mid = (lo + hi) >> 1; if (batch[mid] < g + 1) lo = mid + 1; else hi = mid; }
    int s1 = lo;

    __shared__ float red[4];
    __shared__ float bval;
    float m = -INFINITY;
    for (int i = s0 + tid; i < s1; i += 256) m = fmaxf(m, nsf[i]);
#pragma unroll
    for (int o = 32; o >= 1; o >>= 1) m = fmaxf(m, __shfl_xor(m, o));
    if ((tid & 63) == 0) red[tid >> 6] = m;
    __syncthreads();
    if (tid == 0) bval = fmaxf(fmaxf(red[0], red[1]), fmaxf(red[2], red[3]));
    __syncthreads();
    float bmx = bval;
    float s = 0.f;
    for (int i = s0 + tid; i < s1; i += 256) {
        float e = expf(nsf[i] - bmx);
        out[i] = e;
        s += e;
    }
#pragma unroll
    for (int o = 32; o >= 1; o >>= 1) s += __shfl_xor(s, o);
    __syncthreads();
    if ((tid & 63) == 0) red[tid >> 6] = s;
    __syncthreads();
    if (tid == 0) bval = red[0] + red[1] + red[2] + red[3];
    __syncthreads();
    float inv = 1.f / bval;
    for (int i = s0 + tid; i < s1; i += 256) out[i] *= inv;
}

extern "C" void kernel_launch(void* const* d_in, const int* in_sizes, int n_in,
                              void* d_out, int out_size, void* d_ws, size_t ws_size,
                              hipStream_t stream) {
    const int N = N_NODES, E = N_EDGES;

    const float* x = (const float*)d_in[0];
    const int* ei = (const int*)d_in[1];
    const int* batch = (const int*)d_in[2];
    const float* W1a[3] = {(const float*)d_in[3], (const float*)d_in[7], (const float*)d_in[11]};
    const float* b1a[3] = {(const float*)d_in[4], (const float*)d_in[8], (const float*)d_in[12]};
    const float* W2a[3] = {(const float*)d_in[5], (const float*)d_in[9], (const float*)d_in[13]};
    const float* b2a[3] = {(const float*)d_in[6], (const float*)d_in[10], (const float*)d_in[14]};
    const float* Wm = (const float*)d_in[15];
    const float* bm = (const float*)d_in[16];
    float* out = (float*)d_out;

    const int* srcp = ei;
    const int* dstp = ei + E;

    // workspace layout (~74 MB; csrc_chunk aliases ubuf)
    float* yA = (float*)d_ws;                   // N*64
    float* yB = yA + (size_t)N * 64;            // N*64
    float* ubuf = yB + (size_t)N * 64;          // N*64 (aliases csrc_chunk)
    int* csrc_chunk = (int*)ubuf;               // E ints (6.4MB of ubuf's 12.8MB)
    float* score = ubuf + (size_t)N * 64;       // N
    float* nsf = score + N;                     // N
    int* deg = (int*)(nsf + N);                 // N
    int* rowptr = deg + N;                      // N+1
    int* part = rowptr + N + 1;                 // 64
    int* csr_src = part + 64;                   // E
    unsigned short* locs = (unsigned short*)(csr_src + E);        // CHUNKS*(N+1) u16
    unsigned short* base = locs + (size_t)CHUNKS * NP1;           // CHUNKS*N u16
    unsigned short* lr = base + (size_t)CHUNKS * N;               // E u16

    histsort_kernel<<<CHUNKS, 1024, 0, stream>>>(srcp, dstp, csrc_chunk, locs, lr);

    const int nbScan = (N + 1023) / 1024;  // 49
    base_scan1_kernel<<<nbScan, 1024, 0, stream>>>(locs, base, deg, part, N);
    scan2_kernel<<<1, 64, 0, stream>>>(part, nbScan);
    scan3_kernel<<<nbScan, 1024, 0, stream>>>(deg, part, rowptr, N);

    const int gfBlocks = 8 * ((N / 8 + 3) / 4);
    gatherfill_kernel<<<gfBlocks, 256, 0, stream>>>(csrc_chunk, locs, base, rowptr, csr_src);

    const int gw = 4096;
    gemm0_kernel<<<1024, 256, 0, stream>>>(x, W1a[0], yA, N, gw);

    int aggBlocks = (N / 2 + 3) / 4;  // one wave per node pair

    agg_kernel<<<aggBlocks, 256, 0, stream>>>(yA, rowptr, csr_src, ubuf, N);
    mlpAB_kernel<0><<<1024, 256, 0, stream>>>(ubuf, b1a[0], W2a[0], b2a[0], W1a[1], Wm, yB, score, N, gw);

    agg_kernel<<<aggBlocks, 256, 0, stream>>>(yB, rowptr, csr_src, ubuf, N);
    mlpAB_kernel<1><<<1024, 256, 0, stream>>>(ubuf, b1a[1], W2a[1], b2a[1], W1a[2], Wm, yA, score, N, gw);

    agg_kernel<<<aggBlocks, 256, 0, stream>>>(yA, rowptr, csr_src, ubuf, N);
    mlpA2_kernel<<<1024, 256, 0, stream>>>(ubuf, b1a[2], W2a[2], b2a[2], Wm, score, N, gw);

    edge_softmax_kernel<<<(N + 3) / 4, 256, 0, stream>>>(score, rowptr, csr_src, bm, nsf, N);

    graph_softmax_kernel<<<N_GRAPH, 256, 0, stream>>>(nsf, batch, out, N);
}

// Round 11
// 339.405 us; speedup vs baseline: 1.1305x; 1.1305x over previous
//
#include <hip/hip_runtime.h>
#include <hip/hip_fp16.h>
#include <math.h>

#define N_NODES 50000
#define N_EDGES 1600000
#define N_GRAPH 500
#define CHUNKS 128
#define EPC (N_EDGES / CHUNKS)  // 12500 edges per chunk
#define NP1 (N_NODES + 1)
#define NIT ((EPC + 1023) / 1024)  // 13 edge-iterations per histsort thread

// ---------- helpers ----------
__device__ __forceinline__ float rl(float v, int k) {
    return __int_as_float(__builtin_amdgcn_readlane(__float_as_int(v), k));
}
// accumulate 4 fp16 (packed in uint2) into float4
__device__ __forceinline__ void hacc(float4& a, uint2 w) {
    __half2 h01 = *reinterpret_cast<__half2*>(&w.x);
    __half2 h23 = *reinterpret_cast<__half2*>(&w.y);
    float2 f01 = __half22float2(h01);
    float2 f23 = __half22float2(h23);
    a.x += f01.x; a.y += f01.y; a.z += f23.x; a.w += f23.y;
}

// ---------- histsort: per-chunk LDS histogram -> in-LDS scan -> chunk-local
//            dst-sorted scatter. Local ranks kept in registers. No global atomics.
__global__ __launch_bounds__(1024) void histsort_kernel(const int* __restrict__ src,
                                                        const int* __restrict__ dst,
                                                        int* __restrict__ csrc_chunk,
                                                        unsigned short* __restrict__ locs) {
    __shared__ unsigned packed[N_NODES / 2];  // 100 KB
    __shared__ unsigned aux[1024];
    const int c = blockIdx.x;
    const int s0 = c * EPC;
    const int tid = threadIdx.x;

    for (int i = tid; i < N_NODES / 2; i += 1024) packed[i] = 0;
    __syncthreads();

    unsigned short lrv[NIT];
#pragma unroll
    for (int it = 0; it < NIT; it++) {
        int e = s0 + it * 1024 + tid;
        if (e < s0 + EPC) {
            int d = dst[e];
            int sh = (d & 1) * 16;
            unsigned old = atomicAdd(&packed[d >> 1], 1u << sh);
            lrv[it] = (unsigned short)((old >> sh) & 0xffffu);
        }
    }
    __syncthreads();

    // in-place exclusive scan over 50000 16-bit counters (prefix <= 12500 fits 16b)
    const int W = 25;
    int w0 = tid * W;
    int w1 = min(w0 + W, N_NODES / 2);
    unsigned run = 0;
    for (int i = w0; i < w1; i++) {
        unsigned v = packed[i];
        unsigned lo = v & 0xffffu, hi = v >> 16;
        packed[i] = run | ((run + lo) << 16);
        run += lo + hi;
    }
    aux[tid] = run;
    __syncthreads();
    for (int off = 1; off < 1024; off <<= 1) {
        unsigned t = (tid >= off) ? aux[tid - off] : 0;
        __syncthreads();
        aux[tid] += t;
        __syncthreads();
    }
    unsigned b0 = (tid == 0) ? 0 : aux[tid - 1];
    if (b0) {
        unsigned addv = b0 | (b0 << 16);
        for (int i = w0; i < w1; i++) packed[i] += addv;
    }
    __syncthreads();

    // scatter this chunk's edges into chunk-local dst-sorted order
    int* outc = csrc_chunk + (size_t)c * EPC;
#pragma unroll
    for (int it = 0; it < NIT; it++) {
        int e = s0 + it * 1024 + tid;
        if (e < s0 + EPC) {
            int d = dst[e];
            unsigned pw = packed[d >> 1];
            unsigned loc = (d & 1) ? (pw >> 16) : (pw & 0xffffu);
            outc[loc + lrv[it]] = src[e];
        }
    }
    // emit loc per node (+ sentinel)
    unsigned short* lc = locs + (size_t)c * NP1;
    for (int d = tid; d <= N_NODES; d += 1024) {
        unsigned short loc;
        if (d == N_NODES) {
            loc = (unsigned short)EPC;
        } else {
            unsigned pw = packed[d >> 1];
            loc = (unsigned short)((d & 1) ? (pw >> 16) : (pw & 0xffffu));
        }
        lc[d] = loc;
    }
}

// ---------- base + scan1 fused ----------
__global__ __launch_bounds__(1024) void base_scan1_kernel(const unsigned short* __restrict__ locs,
                                                          unsigned short* __restrict__ base,
                                                          int* __restrict__ deg,
                                                          int* __restrict__ part, int N) {
    int d = blockIdx.x * 1024 + threadIdx.x;
    int run = 0;
    if (d < N) {
#pragma unroll 8
        for (int c = 0; c < CHUNKS; c++) {
            int l0 = locs[(size_t)c * NP1 + d];
            int l1 = locs[(size_t)c * NP1 + d + 1];
            base[(size_t)c * N + d] = (unsigned short)run;
            run += l1 - l0;
        }
        deg[d] = run;
    }
    int v = run;
#pragma unroll
    for (int o = 32; o >= 1; o >>= 1) v += __shfl_xor(v, o);
    __shared__ int red[16];
    if ((threadIdx.x & 63) == 0) red[threadIdx.x >> 6] = v;
    __syncthreads();
    if (threadIdx.x == 0) {
        int s = 0;
#pragma unroll
        for (int k = 0; k < 16; k++) s += red[k];
        part[blockIdx.x] = s;
    }
}

__global__ void scan2_kernel(int* __restrict__ part, int nb) {
    int lane = threadIdx.x;
    int v = (lane < nb) ? part[lane] : 0;
    int orig = v;
#pragma unroll
    for (int o = 1; o < 64; o <<= 1) {
        int t = __shfl_up(v, o);
        if (lane >= o) v += t;
    }
    if (lane < nb) part[lane] = v - orig;
    if (lane == nb - 1) part[nb] = v;
}

__global__ __launch_bounds__(1024) void scan3_kernel(const int* __restrict__ deg,
                                                     const int* __restrict__ part,
                                                     int* __restrict__ rowptr, int N) {
    int i = blockIdx.x * 1024 + threadIdx.x;
    int lane = threadIdx.x & 63;
    int w = threadIdx.x >> 6;
    int v = (i < N) ? deg[i] : 0;
    int inc = v;
#pragma unroll
    for (int o = 1; o < 64; o <<= 1) {
        int t = __shfl_up(inc, o);
        if (lane >= o) inc += t;
    }
    __shared__ int wsum[16];
    if (lane == 63) wsum[w] = inc;
    __syncthreads();
    if (threadIdx.x < 16) {
        int x = wsum[threadIdx.x];
        int xo = x;
#pragma unroll
        for (int o = 1; o < 16; o <<= 1) {
            int t = __shfl_up(x, o);
            if ((int)threadIdx.x >= o) x += t;
        }
        wsum[threadIdx.x] = x - xo;
    }
    __syncthreads();
    int b = part[blockIdx.x] + wsum[w];
    if (i < N) {
        rowptr[i] = b + inc - v;
        if (i == N - 1) rowptr[N] = b + inc;
    }
}

// ---------- gatherfill: one wave per node, lane covers 2 chunks ----------
__global__ __launch_bounds__(256) void gatherfill_kernel(const int* __restrict__ csrc_chunk,
                                                         const unsigned short* __restrict__ locs,
                                                         const unsigned short* __restrict__ base,
                                                         const int* __restrict__ rowptr,
                                                         int* __restrict__ csr_src) {
    const int perXcd = N_NODES / 8;  // 6250
    int xcd = blockIdx.x & 7;
    int idx = (blockIdx.x >> 3) * 4 + (threadIdx.x >> 6);
    if (idx >= perXcd) return;
    int wid = xcd * perXcd + idx;
    int lane = threadIdx.x & 63;
    int rp = rowptr[wid];
#pragma unroll
    for (int cc = 0; cc < 2; cc++) {
        int c = lane + cc * 64;
        const unsigned short* lc = locs + (size_t)c * NP1;
        int l0 = lc[wid];
        int l1 = lc[wid + 1];
        int cnt = l1 - l0;
        int ob = rp + (int)base[(size_t)c * N_NODES + wid];
        const int* in = csrc_chunk + (size_t)c * EPC + l0;
        for (int i = 0; i < cnt; i++) csr_src[ob + i] = in[i];
    }
}

// ---------- aggregation on fp16 y: u[d] = y[d] + sum y[src] (fp32 accum) ----------
__global__ __launch_bounds__(256) void agg_kernel(const __half* __restrict__ yh,
                                                  const int* __restrict__ rowptr,
                                                  const int* __restrict__ csr_src,
                                                  float* __restrict__ u, int N) {
    int wid = (blockIdx.x * 256 + threadIdx.x) >> 6;
    int lane = threadIdx.x & 63;
    if (wid >= N) return;
    int q = lane >> 4;   // edge slot 0..3
    int r = lane & 15;   // feature quad 0..15 (4 halves = 8B each)
    int start = rowptr[wid];
    int end = rowptr[wid + 1];
    float4 acc = make_float4(0.f, 0.f, 0.f, 0.f);
    int j = start;
    for (; j + 32 <= end; j += 32) {
        int s0 = csr_src[j + q];
        int s1 = csr_src[j + 4 + q];
        int s2 = csr_src[j + 8 + q];
        int s3 = csr_src[j + 12 + q];
        int s4 = csr_src[j + 16 + q];
        int s5 = csr_src[j + 20 + q];
        int s6 = csr_src[j + 24 + q];
        int s7 = csr_src[j + 28 + q];
        uint2 w0 = *(const uint2*)(yh + (size_t)s0 * 64 + r * 4);
        uint2 w1 = *(const uint2*)(yh + (size_t)s1 * 64 + r * 4);
        uint2 w2 = *(const uint2*)(yh + (size_t)s2 * 64 + r * 4);
        uint2 w3 = *(const uint2*)(yh + (size_t)s3 * 64 + r * 4);
        uint2 w4 = *(const uint2*)(yh + (size_t)s4 * 64 + r * 4);
        uint2 w5 = *(const uint2*)(yh + (size_t)s5 * 64 + r * 4);
        uint2 w6 = *(const uint2*)(yh + (size_t)s6 * 64 + r * 4);
        uint2 w7 = *(const uint2*)(yh + (size_t)s7 * 64 + r * 4);
        hacc(acc, w0); hacc(acc, w1); hacc(acc, w2); hacc(acc, w3);
        hacc(acc, w4); hacc(acc, w5); hacc(acc, w6); hacc(acc, w7);
    }
#pragma unroll
    for (int m = 0; m < 8; m++) {
        int e = j + 4 * m + q;
        if (e < end) {
            int s = csr_src[e];
            uint2 w = *(const uint2*)(yh + (size_t)s * 64 + r * 4);
            hacc(acc, w);
        }
    }
    acc.x += __shfl_xor(acc.x, 16);
    acc.y += __shfl_xor(acc.y, 16);
    acc.z += __shfl_xor(acc.z, 16);
    acc.w += __shfl_xor(acc.w, 16);
    acc.x += __shfl_xor(acc.x, 32);
    acc.y += __shfl_xor(acc.y, 32);
    acc.z += __shfl_xor(acc.z, 32);
    acc.w += __shfl_xor(acc.w, 32);
    if (lane < 16) {
        uint2 w = *(const uint2*)(yh + (size_t)wid * 64 + r * 4);
        hacc(acc, w);
        *(float4*)(u + (size_t)wid * 64 + r * 4) = acc;
    }
}

// ---------- gemm0: y0 = x @ W1_0 (fp32 math, fp16 store) ----------
__global__ __launch_bounds__(256) void gemm0_kernel(const float* __restrict__ x,
                                                    const float* __restrict__ W1,
                                                    __half* __restrict__ y0,
                                                    int N, int totalWaves) {
    int lane = threadIdx.x & 63;
    int wid = (blockIdx.x * 256 + threadIdx.x) >> 6;
    float wA[64], wB[64];
#pragma unroll
    for (int k = 0; k < 64; k++) wA[k] = W1[k * 64 + lane];
#pragma unroll
    for (int k = 0; k < 64; k++) wB[k] = W1[(64 + k) * 64 + lane];
    for (int node = wid; node < N; node += totalWaves) {
        float xa = x[(size_t)node * 128 + lane];
        float xb = x[(size_t)node * 128 + 64 + lane];
        float a0 = 0.f, a1 = 0.f, a2 = 0.f, a3 = 0.f;
#pragma unroll
        for (int k = 0; k < 64; k += 4) {
            a0 = fmaf(rl(xa, k + 0), wA[k + 0], a0);
            a1 = fmaf(rl(xa, k + 1), wA[k + 1], a1);
            a2 = fmaf(rl(xa, k + 2), wA[k + 2], a2);
            a3 = fmaf(rl(xa, k + 3), wA[k + 3], a3);
        }
#pragma unroll
        for (int k = 0; k < 64; k += 4) {
            a0 = fmaf(rl(xb, k + 0), wB[k + 0], a0);
            a1 = fmaf(rl(xb, k + 1), wB[k + 1], a1);
            a2 = fmaf(rl(xb, k + 2), wB[k + 2], a2);
            a3 = fmaf(rl(xb, k + 3), wB[k + 3], a3);
        }
        y0[(size_t)node * 64 + lane] = __float2half((a0 + a1) + (a2 + a3));
    }
}

// ---------- fused mlpAB (layers 0,1): fp32 u in, fp16 ynext out ----------
template <int LAYER>
__global__ __launch_bounds__(256) void mlpAB_kernel(const float* __restrict__ u,
                                                    const float* __restrict__ b1,
                                                    const float* __restrict__ W2,
                                                    const float* __restrict__ b2,
                                                    const float* __restrict__ W1n,
                                                    const float* __restrict__ Wm,
                                                    __half* __restrict__ ynext,
                                                    float* __restrict__ score,
                                                    int N, int totalWaves) {
    int lane = threadIdx.x & 63;
    int wid = (blockIdx.x * 256 + threadIdx.x) >> 6;
    float w2[64], w1[64];
#pragma unroll
    for (int k = 0; k < 64; k++) w2[k] = W2[k * 64 + lane];
#pragma unroll
    for (int k = 0; k < 64; k++) w1[k] = W1n[k * 64 + lane];
    float bb1 = b1[lane], bb2 = b2[lane], wm = Wm[LAYER * 64 + lane];

    int node = wid;
    float uin = (node < N) ? u[(size_t)node * 64 + lane] : 0.f;
    for (; node < N; node += totalWaves) {
        int nn = node + totalWaves;
        float unext = (nn < N) ? u[(size_t)nn * 64 + lane] : 0.f;
        float t = fmaxf(uin + bb1, 0.f);
        float a0 = 0.f, a1 = 0.f, a2 = 0.f, a3 = 0.f;
#pragma unroll
        for (int k = 0; k < 64; k += 4) {
            a0 = fmaf(rl(t, k + 0), w2[k + 0], a0);
            a1 = fmaf(rl(t, k + 1), w2[k + 1], a1);
            a2 = fmaf(rl(t, k + 2), w2[k + 2], a2);
            a3 = fmaf(rl(t, k + 3), w2[k + 3], a3);
        }
        float h = fmaxf(bb2 + ((a0 + a1) + (a2 + a3)), 0.f);
        float p = h * wm;
#pragma unroll
        for (int o = 32; o >= 1; o >>= 1) p += __shfl_xor(p, o);
        if (lane == 0) {
            if (LAYER == 0) score[node] = p;
            else score[node] += p;
        }
        float y0 = 0.f, y1 = 0.f, y2 = 0.f, y3 = 0.f;
#pragma unroll
        for (int k = 0; k < 64; k += 4) {
            y0 = fmaf(rl(h, k + 0), w1[k + 0], y0);
            y1 = fmaf(rl(h, k + 1), w1[k + 1], y1);
            y2 = fmaf(rl(h, k + 2), w1[k + 2], y2);
            y3 = fmaf(rl(h, k + 3), w1[k + 3], y3);
        }
        ynext[(size_t)node * 64 + lane] = __float2half((y0 + y1) + (y2 + y3));
        uin = unext;
    }
}

// ---------- mlpA2 (layer 2) ----------
__global__ __launch_bounds__(256) void mlpA2_kernel(const float* __restrict__ u,
                                                    const float* __restrict__ b1,
                                                    const float* __restrict__ W2,
                                                    const float* __restrict__ b2,
                                                    const float* __restrict__ Wm,
                                                    float* __restrict__ score,
                                                    int N, int totalWaves) {
    int lane = threadIdx.x & 63;
    int wid = (blockIdx.x * 256 + threadIdx.x) >> 6;
    float w2[64];
#pragma unroll
    for (int k = 0; k < 64; k++) w2[k] = W2[k * 64 + lane];
    float bb1 = b1[lane], bb2 = b2[lane], wm = Wm[2 * 64 + lane];

    int node = wid;
    float uin = (node < N) ? u[(size_t)node * 64 + lane] : 0.f;
    for (; node < N; node += totalWaves) {
        int nn = node + totalWaves;
        float unext = (nn < N) ? u[(size_t)nn * 64 + lane] : 0.f;
        float t = fmaxf(uin + bb1, 0.f);
        float a0 = 0.f, a1 = 0.f, a2 = 0.f, a3 = 0.f;
#pragma unroll
        for (int k = 0; k < 64; k += 4) {
            a0 = fmaf(rl(t, k + 0), w2[k + 0], a0);
            a1 = fmaf(rl(t, k + 1), w2[k + 1], a1);
            a2 = fmaf(rl(t, k + 2), w2[k + 2], a2);
            a3 = fmaf(rl(t, k + 3), w2[k + 3], a3);
        }
        float h = bb2 + ((a0 + a1) + (a2 + a3));
        float p = h * wm;
#pragma unroll
        for (int o = 32; o >= 1; o >>= 1) p += __shfl_xor(p, o);
        if (lane == 0) score[node] += p;
        uin = unext;
    }
}

// ---------- edge softmax + new_score ----------
__global__ __launch_bounds__(256) void edge_softmax_kernel(const float* __restrict__ score,
                                                           const int* __restrict__ rowptr,
                                                           const int* __restrict__ csr_src,
                                                           const float* __restrict__ bm,
                                                           float* __restrict__ nsf, int N) {
    int wid = (blockIdx.x * blockDim.x + threadIdx.x) >> 6;
    int lane = threadIdx.x & 63;
    if (wid >= N) return;
    float b = bm[0];
    float sd = score[wid] + b;
    int start = rowptr[wid];
    int end = rowptr[wid + 1];
    bool has0 = (start + lane < end);
    float ss0 = 0.f;
    float m = -INFINITY;
    if (has0) {
        ss0 = score[csr_src[start + lane]] + b;
        m = ss0 * sd;
    }
    for (int j = start + 64 + lane; j < end; j += 64) {
        float ss = score[csr_src[j]] + b;
        m = fmaxf(m, ss * sd);
    }
#pragma unroll
    for (int o = 32; o >= 1; o >>= 1) m = fmaxf(m, __shfl_xor(m, o));
    float se = 0.f, swe = 0.f;
    if (m > -INFINITY) {
        if (has0) {
            float e0 = expf(ss0 * sd - m);
            se += e0;
            swe += ss0 * e0;
        }
        for (int j = start + 64 + lane; j < end; j += 64) {
            float ss = score[csr_src[j]] + b;
            float e = expf(ss * sd - m);
            se += e;
            swe += ss * e;
        }
#pragma unroll
        for (int o = 32; o >= 1; o >>= 1) {
            se += __shfl_xor(se, o);
            swe += __shfl_xor(swe, o);
        }
    }
    float ns = (se > 0.f) ? (swe / se) : 0.f;
    if (lane == 0) nsf[wid] = sd + ns;
}

// ---------- fused graph-segment softmax: one block per graph ----------
__global__ __launch_bounds__(256) void graph_softmax_kernel(const float* __restrict__ nsf,
                                                            const int* __restrict__ batch,
                                                            float* __restrict__ out, int N) {
    int g = blockIdx.x;
    int tid = threadIdx.x;
    int lo = 0, hi = N;
    while (lo < hi) { int mid = (lo + hi) >> 1; if (batch[mid] < g) lo = mid + 1; else hi = mid; }
    int s0 = lo;
    hi = N;
    while (lo < hi) { int mid = (lo + hi) >> 1; if (batch[mid] < g + 1) lo = mid + 1; else hi = mid; }
    int s1 = lo;

    __shared__ float red[4];
    __shared__ float bval;
    float m = -INFINITY;
    for (int i = s0 + tid; i < s1; i += 256) m = fmaxf(m, nsf[i]);
#pragma unroll
    for (int o = 32; o >= 1; o >>= 1) m = fmaxf(m, __shfl_xor(m, o));
    if ((tid & 63) == 0) red[tid >> 6] = m;
    __syncthreads();
    if (tid == 0) bval = fmaxf(fmaxf(red[0], red[1]), fmaxf(red[2], red[3]));
    __syncthreads();
    float bmx = bval;
    float s = 0.f;
    for (int i = s0 + tid; i < s1; i += 256) {
        float e = expf(nsf[i] - bmx);
        out[i] = e;
        s += e;
    }
#pragma unroll
    for (int o = 32; o >= 1; o >>= 1) s += __shfl_xor(s, o);
    __syncthreads();
    if ((tid & 63) == 0) red[tid >> 6] = s;
    __syncthreads();
    if (tid == 0) bval = red[0] + red[1] + red[2] + red[3];
    __syncthreads();
    float inv = 1.f / bval;
    for (int i = s0 + tid; i < s1; i += 256) out[i] *= inv;
}

extern "C" void kernel_launch(void* const* d_in, const int* in_sizes, int n_in,
                              void* d_out, int out_size, void* d_ws, size_t ws_size,
                              hipStream_t stream) {
    const int N = N_NODES, E = N_EDGES;

    const float* x = (const float*)d_in[0];
    const int* ei = (const int*)d_in[1];
    const int* batch = (const int*)d_in[2];
    const float* W1a[3] = {(const float*)d_in[3], (const float*)d_in[7], (const float*)d_in[11]};
    const float* b1a[3] = {(const float*)d_in[4], (const float*)d_in[8], (const float*)d_in[12]};
    const float* W2a[3] = {(const float*)d_in[5], (const float*)d_in[9], (const float*)d_in[13]};
    const float* b2a[3] = {(const float*)d_in[6], (const float*)d_in[10], (const float*)d_in[14]};
    const float* Wm = (const float*)d_in[15];
    const float* bm = (const float*)d_in[16];
    float* out = (float*)d_out;

    const int* srcp = ei;
    const int* dstp = ei + E;

    // workspace layout (~59 MB; csrc_chunk aliases ubuf — ubuf first written after gatherfill)
    float* ubuf = (float*)d_ws;                 // N*64 f32 (aliases csrc_chunk)
    int* csrc_chunk = (int*)ubuf;               // E ints (6.4MB of ubuf's 12.8MB)
    __half* yA = (__half*)(ubuf + (size_t)N * 64);  // N*64 f16
    __half* yB = yA + (size_t)N * 64;               // N*64 f16
    float* score = (float*)(yB + (size_t)N * 64);   // N
    float* nsf = score + N;                     // N
    int* deg = (int*)(nsf + N);                 // N
    int* rowptr = deg + N;                      // N+1
    int* part = rowptr + N + 1;                 // 64
    int* csr_src = part + 64;                   // E
    unsigned short* locs = (unsigned short*)(csr_src + E);        // CHUNKS*(N+1) u16
    unsigned short* base = locs + (size_t)CHUNKS * NP1;           // CHUNKS*N u16

    histsort_kernel<<<CHUNKS, 1024, 0, stream>>>(srcp, dstp, csrc_chunk, locs);

    const int nbScan = (N + 1023) / 1024;  // 49
    base_scan1_kernel<<<nbScan, 1024, 0, stream>>>(locs, base, deg, part, N);
    scan2_kernel<<<1, 64, 0, stream>>>(part, nbScan);
    scan3_kernel<<<nbScan, 1024, 0, stream>>>(deg, part, rowptr, N);

    const int gfBlocks = 8 * ((N / 8 + 3) / 4);
    gatherfill_kernel<<<gfBlocks, 256, 0, stream>>>(csrc_chunk, locs, base, rowptr, csr_src);

    const int gw = 4096;
    gemm0_kernel<<<1024, 256, 0, stream>>>(x, W1a[0], yA, N, gw);

    int aggBlocks = (N + 3) / 4;  // one wave per node

    agg_kernel<<<aggBlocks, 256, 0, stream>>>(yA, rowptr, csr_src, ubuf, N);
    mlpAB_kernel<0><<<1024, 256, 0, stream>>>(ubuf, b1a[0], W2a[0], b2a[0], W1a[1], Wm, yB, score, N, gw);

    agg_kernel<<<aggBlocks, 256, 0, stream>>>(yB, rowptr, csr_src, ubuf, N);
    mlpAB_kernel<1><<<1024, 256, 0, stream>>>(ubuf, b1a[1], W2a[1], b2a[1], W1a[2], Wm, yA, score, N, gw);

    agg_kernel<<<aggBlocks, 256, 0, stream>>>(yA, rowptr, csr_src, ubuf, N);
    mlpA2_kernel<<<1024, 256, 0, stream>>>(ubuf, b1a[2], W2a[2], b2a[2], Wm, score, N, gw);

    edge_softmax_kernel<<<(N + 3) / 4, 256, 0, stream>>>(score, rowptr, csr_src, bm, nsf, N);

    graph_softmax_kernel<<<N_GRAPH, 256, 0, stream>>>(nsf, batch, out, N);
}